// Round 3
// baseline (63.337 us; speedup 1.0000x reference)
//
#include <hip/hip_runtime.h>
#include <math.h>

// Problem constants (fixed by the reference)
#define Bn  32
#define Qn  900
#define Cn  92
#define TI  4            // i-rows per block
#define NT  (Qn / TI)    // 225 i-tiles per batch
#define BLK 256

__global__ __launch_bounds__(BLK) void hungarian_cost_kernel(
    const float* __restrict__ logits,   // [B,Q,C]
    const float* __restrict__ pboxes,   // [B,Q,4] cxcywh
    const float* __restrict__ gboxes,   // [B,Q,4] cxcywh
    const float* __restrict__ area,     // [B,Q]
    const int*   __restrict__ labels,   // [B,Q]
    float* __restrict__ out)            // [B,Q,Q]
{
    __shared__ float4 s_bj[Qn];        // target boxes, xyxy          (14400 B)
    __shared__ float  s_area[Qn];      //                              (3600 B)
    __shared__ int    s_lab[Qn];       //                              (3600 B)
    __shared__ float  s_prob[TI][Cn];  // softmax rows                 (1472 B)
    __shared__ float4 s_pred[TI];      // pred boxes, xyxy             (64 B)

    const int blk = blockIdx.x;
    const int b   = blk / NT;
    const int i0  = (blk - b * NT) * TI;
    const int tid = threadIdx.x;

    // ---- Phase 1: stage j-side data into LDS ----
    const float4* gb4 = (const float4*)(gboxes + (size_t)b * Qn * 4);
    const float*  ga  = area   + (size_t)b * Qn;
    const int*    gl  = labels + (size_t)b * Qn;
    for (int j = tid; j < Qn; j += BLK) {
        float4 c = gb4[j];
        float4 x;
        x.x = c.x - 0.5f * c.z;
        x.y = c.y - 0.5f * c.w;
        x.z = c.x + 0.5f * c.z;
        x.w = c.y + 0.5f * c.w;
        s_bj[j]   = x;
        s_area[j] = ga[j];
        s_lab[j]  = gl[j];
    }

    // ---- Phase 2: softmax, one wave per i-row (4 waves = TI rows) ----
    {
        const int wave = tid >> 6;
        const int lane = tid & 63;
        const int r    = i0 + wave;
        const float* lrow = logits + ((size_t)(b * Qn + r)) * Cn;
        float x0 = lrow[lane];                                   // 64 < 92: always valid
        float x1 = (lane + 64 < Cn) ? lrow[lane + 64] : -INFINITY;
        float m = fmaxf(x0, x1);
        #pragma unroll
        for (int off = 32; off; off >>= 1)
            m = fmaxf(m, __shfl_xor(m, off));
        float e0 = __expf(x0 - m);
        float e1 = (lane + 64 < Cn) ? __expf(x1 - m) : 0.0f;
        float s = e0 + e1;
        #pragma unroll
        for (int off = 32; off; off >>= 1)
            s += __shfl_xor(s, off);
        float inv = 1.0f / s;
        s_prob[wave][lane] = e0 * inv;
        if (lane + 64 < Cn) s_prob[wave][lane + 64] = e1 * inv;
        if (lane == 0) {
            float4 c = ((const float4*)(pboxes + (size_t)b * Qn * 4))[r];
            float4 x;
            x.x = c.x - 0.5f * c.z;
            x.y = c.y - 0.5f * c.w;
            x.z = c.x + 0.5f * c.z;
            x.w = c.y + 0.5f * c.w;
            s_pred[wave] = x;
        }
    }
    __syncthreads();

    // ---- Phase 3: compute cost, float4-vectorized writes ----
    float* orow_base = out + ((size_t)b * Qn + i0) * Qn;
    for (int f = tid; f < TI * NT; f += BLK) {
        const int il = f / NT;            // 0..3
        const int j4 = (f - il * NT) * 4; // j of first of 4 outputs

        const float4 P     = s_pred[il];
        const float  areaP = (P.z - P.x) * (P.w - P.y);
        const float* prow  = s_prob[il];

        float r0, r1, r2, r3;
        #pragma unroll
        for (int k = 0; k < 4; ++k) {
            const int j = j4 + k;
            const float4 Bx = s_bj[j];

            // L1 in cxcywh recovered from xyxy diffs:
            // |dcx| = 0.5|dx0+dx1|, |dw| = |dx1-dx0|
            float dx0 = P.x - Bx.x, dy0 = P.y - Bx.y;
            float dx1 = P.z - Bx.z, dy1 = P.w - Bx.w;
            float cost_bbox = 0.25f * (0.5f * (fabsf(dx0 + dx1) + fabsf(dy0 + dy1))
                                       + fabsf(dx1 - dx0) + fabsf(dy1 - dy0));

            float areaB = (Bx.z - Bx.x) * (Bx.w - Bx.y);
            float ltx = fmaxf(P.x, Bx.x), lty = fmaxf(P.y, Bx.y);
            float rbx = fminf(P.z, Bx.z), rby = fminf(P.w, Bx.w);
            float iw = fmaxf(rbx - ltx, 0.0f), ih = fmaxf(rby - lty, 0.0f);
            float inter = iw * ih;
            float uni   = areaP + areaB - inter;
            float iou   = inter / uni;

            float ex0 = fminf(P.x, Bx.x), ey0 = fminf(P.y, Bx.y);
            float ex1 = fmaxf(P.z, Bx.z), ey1 = fmaxf(P.w, Bx.w);
            float ew = fmaxf(ex1 - ex0, 0.0f), eh = fmaxf(ey1 - ey0, 0.0f);
            float enc = ew * eh;
            float giou = iou - (enc - uni) / enc;

            float cost_class = -prow[s_lab[j]];

            float c = cost_bbox + cost_class - giou;
            c = (s_area[j] > 0.0f) ? c : 100000000.0f;
            if (k == 0) r0 = c; else if (k == 1) r1 = c; else if (k == 2) r2 = c; else r3 = c;
        }
        float4 res = make_float4(r0, r1, r2, r3);
        // row base = (b*Q + i0 + il)*Q floats = multiple of 3600 B; j4*4 B is 16B-aligned
        ((float4*)(orow_base + (size_t)il * Qn))[j4 >> 2] = res;
    }
}

extern "C" void kernel_launch(void* const* d_in, const int* in_sizes, int n_in,
                              void* d_out, int out_size, void* d_ws, size_t ws_size,
                              hipStream_t stream) {
    const float* logits = (const float*)d_in[0];  // pred_logits [B,Q,C]
    const float* pboxes = (const float*)d_in[1];  // pred_boxes  [B,Q,4]
    const float* gboxes = (const float*)d_in[2];  // boxes       [B,Q,4]
    const float* areas  = (const float*)d_in[3];  // area        [B,Q]
    const int*   labels = (const int*)d_in[4];    // labels      [B,Q]
    float* out = (float*)d_out;                   // [B,Q,Q] f32

    hungarian_cost_kernel<<<Bn * NT, BLK, 0, stream>>>(
        logits, pboxes, gboxes, areas, labels, out);
}

// Round 4
// 45.317 us; speedup vs baseline: 1.3976x; 1.3976x over previous
//
#include <hip/hip_runtime.h>
#include <math.h>

// Problem constants (fixed by the reference)
#define Bn  32
#define Qn  900
#define Cn  92
#define TI  12            // i-rows per block (must divide 900)
#define NIT (Qn / TI)     // 75 i-tiles per batch
#define NT  (Qn / 4)      // 225 j-groups of 4
#define BLK 256
#define BIGV 100000000.0f

__global__ __launch_bounds__(BLK) void hungarian_cost_kernel(
    const float* __restrict__ logits,   // [B,Q,C]
    const float* __restrict__ pboxes,   // [B,Q,4] cxcywh
    const float* __restrict__ gboxes,   // [B,Q,4] cxcywh
    const float* __restrict__ area,     // [B,Q]
    const int*   __restrict__ labels,   // [B,Q]
    float* __restrict__ out)            // [B,Q,Q]
{
    // SoA j-side staging: lanes read aligned float4 of 4 consecutive j
    // -> stride-16B conflict-free ds_read_b128 (fixes 6.2M bank-conflict cycles)
    __shared__ float s_x0[Qn], s_y0[Qn], s_x1[Qn], s_y1[Qn];
    __shared__ float s_ab[Qn];          // target box area (w*h)
    __shared__ float s_fl[Qn];          // select floor: area>0 ? -FLT_MAX : BIG
    __shared__ int   s_lab[Qn];
    __shared__ float s_prob[TI][Cn];    // softmax rows
    __shared__ float4 s_pred[TI];       // pred boxes xyxy
    __shared__ float  s_predA[TI];      // pred areas

    const int blk = blockIdx.x;
    const int b   = blk / NIT;
    const int i0  = (blk - b * NIT) * TI;
    const int tid = threadIdx.x;

    // ---- Phase 1: stage j-side data (SoA) ----
    const float4* gb4 = (const float4*)(gboxes + (size_t)b * Qn * 4);
    const float*  ga  = area   + (size_t)b * Qn;
    const int*    gl  = labels + (size_t)b * Qn;
    for (int j = tid; j < Qn; j += BLK) {
        float4 c = gb4[j];
        s_x0[j] = c.x - 0.5f * c.z;
        s_y0[j] = c.y - 0.5f * c.w;
        s_x1[j] = c.x + 0.5f * c.z;
        s_y1[j] = c.y + 0.5f * c.w;
        s_ab[j] = c.z * c.w;                              // (x1-x0)*(y1-y0)
        s_fl[j] = (ga[j] > 0.0f) ? -3.402823e38f : BIGV;  // fmax-select trick
        s_lab[j] = gl[j];
    }

    // ---- Phase 2: softmax, one wave per i-row, 3 rows/wave ----
    {
        const int wave = tid >> 6;
        const int lane = tid & 63;
        for (int rr = wave; rr < TI; rr += 4) {
            const int r = i0 + rr;
            const float* lrow = logits + ((size_t)(b * Qn + r)) * Cn;
            float x0 = lrow[lane];                                  // 64 < 92
            float x1 = (lane + 64 < Cn) ? lrow[lane + 64] : -INFINITY;
            float m = fmaxf(x0, x1);
            #pragma unroll
            for (int off = 32; off; off >>= 1)
                m = fmaxf(m, __shfl_xor(m, off));
            float e0 = __expf(x0 - m);
            float e1 = (lane + 64 < Cn) ? __expf(x1 - m) : 0.0f;
            float s = e0 + e1;
            #pragma unroll
            for (int off = 32; off; off >>= 1)
                s += __shfl_xor(s, off);
            float inv = __builtin_amdgcn_rcpf(s);
            s_prob[rr][lane] = e0 * inv;
            if (lane + 64 < Cn) s_prob[rr][lane + 64] = e1 * inv;
            if (lane == 0) {
                float4 c = ((const float4*)(pboxes + (size_t)b * Qn * 4))[r];
                float4 x;
                x.x = c.x - 0.5f * c.z;
                x.y = c.y - 0.5f * c.w;
                x.z = c.x + 0.5f * c.z;
                x.w = c.y + 0.5f * c.w;
                s_pred[rr]  = x;
                s_predA[rr] = c.z * c.w;
            }
        }
    }
    __syncthreads();

    // ---- Phase 3: cost, 4 j per thread, float4 writes ----
    float* obase = out + ((size_t)b * Qn + i0) * Qn;
    for (int f = tid; f < TI * NT; f += BLK) {
        const int il = f / NT;            // 0..TI-1 (magic-mul)
        const int j4 = (f - il * NT) * 4; // first of 4 consecutive j

        const float4 P     = s_pred[il];
        const float  areaP = s_predA[il];
        const float* prow  = s_prob[il];

        const float4 X0 = *(const float4*)&s_x0[j4];
        const float4 Y0 = *(const float4*)&s_y0[j4];
        const float4 X1 = *(const float4*)&s_x1[j4];
        const float4 Y1 = *(const float4*)&s_y1[j4];
        const float4 AB = *(const float4*)&s_ab[j4];
        const float4 FL = *(const float4*)&s_fl[j4];
        const int4   LB = *(const int4*)&s_lab[j4];

        auto cost1 = [&](float bx0, float by0, float bx1, float by1,
                         float ab, float fl, int lb) -> float {
            float dx0 = P.x - bx0, dy0 = P.y - by0;
            float dx1 = P.z - bx1, dy1 = P.w - by1;
            // mean-L1 in cxcywh from xyxy diffs
            float s1 = fabsf(dx0 + dx1) + fabsf(dy0 + dy1);
            float s2 = fabsf(dx1 - dx0) + fabsf(dy1 - dy0);
            float bb = __builtin_fmaf(s1, 0.125f, 0.25f * s2);
            // intersection
            float iw = fminf(P.z, bx1) - fmaxf(P.x, bx0);
            float ih = fminf(P.w, by1) - fmaxf(P.y, by0);
            iw = fmaxf(iw, 0.0f); ih = fmaxf(ih, 0.0f);
            float inter = iw * ih;
            float uni = areaP + ab - inter;
            // enclosing box (always non-negative extents)
            float ew = fmaxf(P.z, bx1) - fminf(P.x, bx0);
            float eh = fmaxf(P.w, by1) - fminf(P.y, by0);
            float enc = ew * eh;
            float rU = __builtin_amdgcn_rcpf(uni);
            float rE = __builtin_amdgcn_rcpf(enc);
            // cost = bb - prob - (inter/uni + uni/enc - 1)
            float g = __builtin_fmaf(inter, rU,
                      __builtin_fmaf(uni, rE, prow[lb] - 1.0f));
            float c = bb - g;
            return fmaxf(c, fl);  // fl = -FLT_MAX (keep c) or BIG (override)
        };

        float4 res;
        res.x = cost1(X0.x, Y0.x, X1.x, Y1.x, AB.x, FL.x, LB.x);
        res.y = cost1(X0.y, Y0.y, X1.y, Y1.y, AB.y, FL.y, LB.y);
        res.z = cost1(X0.z, Y0.z, X1.z, Y1.z, AB.z, FL.z, LB.z);
        res.w = cost1(X0.w, Y0.w, X1.w, Y1.w, AB.w, FL.w, LB.w);

        ((float4*)(obase + (size_t)il * Qn))[j4 >> 2] = res;
    }
}

extern "C" void kernel_launch(void* const* d_in, const int* in_sizes, int n_in,
                              void* d_out, int out_size, void* d_ws, size_t ws_size,
                              hipStream_t stream) {
    const float* logits = (const float*)d_in[0];  // pred_logits [B,Q,C]
    const float* pboxes = (const float*)d_in[1];  // pred_boxes  [B,Q,4]
    const float* gboxes = (const float*)d_in[2];  // boxes       [B,Q,4]
    const float* areas  = (const float*)d_in[3];  // area        [B,Q]
    const int*   labels = (const int*)d_in[4];    // labels      [B,Q]
    float* out = (float*)d_out;                   // [B,Q,Q] f32

    hungarian_cost_kernel<<<Bn * NIT, BLK, 0, stream>>>(
        logits, pboxes, gboxes, areas, labels, out);
}

// Round 6
// 43.274 us; speedup vs baseline: 1.4636x; 1.0472x over previous
//
#include <hip/hip_runtime.h>
#include <math.h>

// Problem constants (fixed by the reference)
#define Bn  32
#define Qn  900
#define Cn  92
#define TI  12            // i-rows per block (divides 900)
#define NIT (Qn / TI)     // 75 i-tiles per batch
#define NG  (Qn / 4)      // 225 j-groups of 4 (one per thread)
#define BLK 256
#define BIGV 100000000.0f
#define NEGINF -3.402823e38f

typedef float f32x4 __attribute__((ext_vector_type(4)));  // native vector: OK for nontemporal builtin

__global__ __launch_bounds__(BLK) void hungarian_cost_kernel(
    const float* __restrict__ logits,   // [B,Q,C]
    const float* __restrict__ pboxes,   // [B,Q,4] cxcywh
    const float* __restrict__ gboxes,   // [B,Q,4] cxcywh
    const float* __restrict__ area,     // [B,Q]
    const int*   __restrict__ labels,   // [B,Q]
    float* __restrict__ out)            // [B,Q,Q]
{
    __shared__ float  s_prob[TI][Cn];   // softmax rows      (4416 B)
    __shared__ float4 s_pred[TI];       // pred boxes xyxy   (192 B)
    __shared__ float  s_predA[TI];      // pred areas        (48 B)

    const int blk = blockIdx.x;
    const int b   = blk / NIT;
    const int i0  = (blk - b * NIT) * TI;
    const int tid = threadIdx.x;

    // ---- Phase 1: per-thread j-side loads straight into REGISTERS ----
    // Issued before the softmax phase so global latency hides under it.
    // Thread t owns j = 4t..4t+3. No LDS staging for j-data at all.
    float X0[4], Y0[4], X1[4], Y1[4], AB[4], FL[4];
    int   LB[4];
    if (tid < NG) {
        const float4* gb4 = (const float4*)(gboxes + (size_t)b * Qn * 4) + tid * 4;
        const float4  a4  = ((const float4*)(area   + (size_t)b * Qn))[tid];
        const int4    l4  = ((const int4*)  (labels + (size_t)b * Qn))[tid];
        #pragma unroll
        for (int k = 0; k < 4; ++k) {
            float4 c = gb4[k];
            X0[k] = c.x - 0.5f * c.z;
            Y0[k] = c.y - 0.5f * c.w;
            X1[k] = c.x + 0.5f * c.z;
            Y1[k] = c.y + 0.5f * c.w;
            AB[k] = c.z * c.w;
        }
        FL[0] = (a4.x > 0.0f) ? NEGINF : BIGV;   // fmax-select floor
        FL[1] = (a4.y > 0.0f) ? NEGINF : BIGV;
        FL[2] = (a4.z > 0.0f) ? NEGINF : BIGV;
        FL[3] = (a4.w > 0.0f) ? NEGINF : BIGV;
        LB[0] = l4.x; LB[1] = l4.y; LB[2] = l4.z; LB[3] = l4.w;
    }

    // ---- Phase 2: softmax, one wave per i-row, 3 rows/wave ----
    {
        const int wave = tid >> 6;
        const int lane = tid & 63;
        #pragma unroll
        for (int rr0 = 0; rr0 < TI; rr0 += 4) {
            const int rr = rr0 + wave;
            const int r  = i0 + rr;
            const float* lrow = logits + ((size_t)(b * Qn + r)) * Cn;
            float x0 = lrow[lane];                                  // 64 < 92
            float x1 = (lane + 64 < Cn) ? lrow[lane + 64] : -INFINITY;
            float m = fmaxf(x0, x1);
            #pragma unroll
            for (int off = 32; off; off >>= 1)
                m = fmaxf(m, __shfl_xor(m, off));
            float e0 = __expf(x0 - m);
            float e1 = (lane + 64 < Cn) ? __expf(x1 - m) : 0.0f;
            float s = e0 + e1;
            #pragma unroll
            for (int off = 32; off; off >>= 1)
                s += __shfl_xor(s, off);
            float inv = __builtin_amdgcn_rcpf(s);
            s_prob[rr][lane] = e0 * inv;
            if (lane + 64 < Cn) s_prob[rr][lane + 64] = e1 * inv;
            if (lane == 0) {
                float4 c = ((const float4*)(pboxes + (size_t)b * Qn * 4))[r];
                float4 x;
                x.x = c.x - 0.5f * c.z;
                x.y = c.y - 0.5f * c.w;
                x.z = c.x + 0.5f * c.z;
                x.w = c.y + 0.5f * c.w;
                s_pred[rr]  = x;
                s_predA[rr] = c.z * c.w;
            }
        }
    }
    __syncthreads();

    // ---- Phase 3: loop i-rows; j-data stays in registers ----
    if (tid < NG) {
        float* obase = out + ((size_t)(b * Qn + i0)) * Qn + tid * 4;
        for (int il = 0; il < TI; ++il) {
            const float4 P     = s_pred[il];     // broadcast read (free)
            const float  areaP = s_predA[il];
            const float* prow  = s_prob[il];

            float r[4];
            #pragma unroll
            for (int k = 0; k < 4; ++k) {
                float dx0 = P.x - X0[k], dy0 = P.y - Y0[k];
                float dx1 = P.z - X1[k], dy1 = P.w - Y1[k];
                // mean-L1 in cxcywh recovered from xyxy diffs
                float s1 = fabsf(dx0 + dx1) + fabsf(dy0 + dy1);
                float s2 = fabsf(dx1 - dx0) + fabsf(dy1 - dy0);
                float bb = __builtin_fmaf(s1, 0.125f, 0.25f * s2);
                // intersection
                float iw = fminf(P.z, X1[k]) - fmaxf(P.x, X0[k]);
                float ih = fminf(P.w, Y1[k]) - fmaxf(P.y, Y0[k]);
                iw = fmaxf(iw, 0.0f); ih = fmaxf(ih, 0.0f);
                float inter = iw * ih;
                float uni = areaP + AB[k] - inter;
                // smallest enclosing box
                float ew = fmaxf(P.z, X1[k]) - fminf(P.x, X0[k]);
                float eh = fmaxf(P.w, Y1[k]) - fminf(P.y, Y0[k]);
                float enc = ew * eh;
                float rU = __builtin_amdgcn_rcpf(uni);
                float rE = __builtin_amdgcn_rcpf(enc);
                // cost = bb - prob - (inter/uni + uni/enc - 1)
                float g = __builtin_fmaf(inter, rU,
                          __builtin_fmaf(uni, rE, prow[LB[k]] - 1.0f));
                r[k] = fmaxf(bb - g, FL[k]);
            }
            f32x4 res = { r[0], r[1], r[2], r[3] };
            // (b*Q+i0+il)*Q*4B is a multiple of 3600B; +16B*tid stays 16B-aligned
            __builtin_nontemporal_store(res, (f32x4*)(obase + (size_t)il * Qn));
        }
    }
}

extern "C" void kernel_launch(void* const* d_in, const int* in_sizes, int n_in,
                              void* d_out, int out_size, void* d_ws, size_t ws_size,
                              hipStream_t stream) {
    const float* logits = (const float*)d_in[0];  // pred_logits [B,Q,C]
    const float* pboxes = (const float*)d_in[1];  // pred_boxes  [B,Q,4]
    const float* gboxes = (const float*)d_in[2];  // boxes       [B,Q,4]
    const float* areas  = (const float*)d_in[3];  // area        [B,Q]
    const int*   labels = (const int*)d_in[4];    // labels      [B,Q]
    float* out = (float*)d_out;                   // [B,Q,Q] f32

    hungarian_cost_kernel<<<Bn * NIT, BLK, 0, stream>>>(
        logits, pboxes, gboxes, areas, labels, out);
}

// Round 7
// 41.293 us; speedup vs baseline: 1.5338x; 1.0480x over previous
//
#include <hip/hip_runtime.h>
#include <math.h>

// Problem constants (fixed by the reference)
#define Bn  32
#define Qn  900
#define Cn  92
#define TI  12            // i-rows per block (divides 900)
#define NIT (Qn / TI)     // 75 i-tiles per batch
#define NG  (Qn / 4)      // 225 j-groups of 4 (one per thread)
#define BLK 256
#define BIGV 100000000.0f
#define NEGINF -3.402823e38f

typedef float f32x4 __attribute__((ext_vector_type(4)));

__global__ __launch_bounds__(BLK) void hungarian_cost_kernel(
    const float* __restrict__ logits,   // [B,Q,C]
    const float* __restrict__ pboxes,   // [B,Q,4] cxcywh
    const float* __restrict__ gboxes,   // [B,Q,4] cxcywh
    const float* __restrict__ area,     // [B,Q]
    const int*   __restrict__ labels,   // [B,Q]
    float* __restrict__ out)            // [B,Q,Q]
{
    __shared__ float  s_prob[TI][Cn];   // softmax rows, stored as (prob - 1)
    __shared__ float4 s_pred[TI];       // pred boxes xyxy
    __shared__ float  s_predA[TI];      // pred areas

    const int blk = blockIdx.x;
    const int b   = blk / NIT;
    const int i0  = (blk - b * NIT) * TI;
    const int tid = threadIdx.x;

    // ---- Phase 1: per-thread j-side loads straight into registers ----
    float X0[4], Y0[4], X1[4], Y1[4], AB[4], FL[4];
    int   LB[4];
    if (tid < NG) {
        const float4* gb4 = (const float4*)(gboxes + (size_t)b * Qn * 4) + tid * 4;
        const float4  a4  = ((const float4*)(area   + (size_t)b * Qn))[tid];
        const int4    l4  = ((const int4*)  (labels + (size_t)b * Qn))[tid];
        #pragma unroll
        for (int k = 0; k < 4; ++k) {
            float4 c = gb4[k];
            X0[k] = c.x - 0.5f * c.z;
            Y0[k] = c.y - 0.5f * c.w;
            X1[k] = c.x + 0.5f * c.z;
            Y1[k] = c.y + 0.5f * c.w;
            AB[k] = c.z * c.w;
        }
        FL[0] = (a4.x > 0.0f) ? NEGINF : BIGV;   // fmax-select floor
        FL[1] = (a4.y > 0.0f) ? NEGINF : BIGV;
        FL[2] = (a4.z > 0.0f) ? NEGINF : BIGV;
        FL[3] = (a4.w > 0.0f) ? NEGINF : BIGV;
        LB[0] = l4.x; LB[1] = l4.y; LB[2] = l4.z; LB[3] = l4.w;
    } else {
        #pragma unroll
        for (int k = 0; k < 4; ++k) LB[k] = 0;   // keep gather addresses in-bounds
    }

    // ---- Phase 2: softmax, one wave per i-row, 3 rows/wave ----
    {
        const int wave = tid >> 6;
        const int lane = tid & 63;
        #pragma unroll
        for (int rr0 = 0; rr0 < TI; rr0 += 4) {
            const int rr = rr0 + wave;
            const int r  = i0 + rr;
            const float* lrow = logits + ((size_t)(b * Qn + r)) * Cn;
            float x0 = lrow[lane];                                  // 64 < 92
            float x1 = (lane + 64 < Cn) ? lrow[lane + 64] : -INFINITY;
            float m = fmaxf(x0, x1);
            #pragma unroll
            for (int off = 32; off; off >>= 1)
                m = fmaxf(m, __shfl_xor(m, off));
            float e0 = __expf(x0 - m);
            float e1 = (lane + 64 < Cn) ? __expf(x1 - m) : 0.0f;
            float s = e0 + e1;
            #pragma unroll
            for (int off = 32; off; off >>= 1)
                s += __shfl_xor(s, off);
            float inv = __builtin_amdgcn_rcpf(s);
            s_prob[rr][lane] = __builtin_fmaf(e0, inv, -1.0f);      // store prob-1
            if (lane + 64 < Cn) s_prob[rr][lane + 64] = __builtin_fmaf(e1, inv, -1.0f);
            if (lane == 0) {
                float4 c = ((const float4*)(pboxes + (size_t)b * Qn * 4))[r];
                float4 x;
                x.x = c.x - 0.5f * c.z;
                x.y = c.y - 0.5f * c.w;
                x.z = c.x + 0.5f * c.z;
                x.w = c.y + 0.5f * c.w;
                s_pred[rr]  = x;
                s_predA[rr] = c.z * c.w;
            }
        }
    }
    __syncthreads();

    // ---- Pre-gather ALL class-prob values into registers (one LDS burst) ----
    float pm[TI * 4];
    #pragma unroll
    for (int il = 0; il < TI; ++il) {
        #pragma unroll
        for (int k = 0; k < 4; ++k)
            pm[il * 4 + k] = s_prob[il][LB[k]];
    }

    // ---- Phase 3: pure-register compute + nontemporal stores ----
    if (tid < NG) {
        float* obase = out + ((size_t)(b * Qn + i0)) * Qn + tid * 4;
        #pragma unroll
        for (int il = 0; il < TI; ++il) {
            const float4 P     = s_pred[il];     // same-address broadcast (free)
            const float  areaP = s_predA[il];

            float r[4];
            #pragma unroll
            for (int k = 0; k < 4; ++k) {
                float dx0 = P.x - X0[k], dy0 = P.y - Y0[k];
                float dx1 = P.z - X1[k], dy1 = P.w - Y1[k];
                // mean-L1 in cxcywh recovered from xyxy diffs
                float s1 = fabsf(dx0 + dx1) + fabsf(dy0 + dy1);
                float s2 = fabsf(dx1 - dx0) + fabsf(dy1 - dy0);
                float bb = __builtin_fmaf(s1, 0.125f, 0.25f * s2);
                // intersection
                float iw = fminf(P.z, X1[k]) - fmaxf(P.x, X0[k]);
                float ih = fminf(P.w, Y1[k]) - fmaxf(P.y, Y0[k]);
                iw = fmaxf(iw, 0.0f); ih = fmaxf(ih, 0.0f);
                float inter = iw * ih;
                float uni = areaP + AB[k] - inter;
                // smallest enclosing box
                float ew = fmaxf(P.z, X1[k]) - fminf(P.x, X0[k]);
                float eh = fmaxf(P.w, Y1[k]) - fminf(P.y, Y0[k]);
                float enc = ew * eh;
                float rU = __builtin_amdgcn_rcpf(uni);
                float rE = __builtin_amdgcn_rcpf(enc);
                // cost = bb - ((prob-1) + inter/uni + uni/enc)
                float g = __builtin_fmaf(inter, rU,
                          __builtin_fmaf(uni, rE, pm[il * 4 + k]));
                r[k] = fmaxf(bb - g, FL[k]);
            }
            f32x4 res = { r[0], r[1], r[2], r[3] };
            __builtin_nontemporal_store(res, (f32x4*)(obase + (size_t)il * Qn));
        }
    }
}

extern "C" void kernel_launch(void* const* d_in, const int* in_sizes, int n_in,
                              void* d_out, int out_size, void* d_ws, size_t ws_size,
                              hipStream_t stream) {
    const float* logits = (const float*)d_in[0];  // pred_logits [B,Q,C]
    const float* pboxes = (const float*)d_in[1];  // pred_boxes  [B,Q,4]
    const float* gboxes = (const float*)d_in[2];  // boxes       [B,Q,4]
    const float* areas  = (const float*)d_in[3];  // area        [B,Q]
    const int*   labels = (const int*)d_in[4];    // labels      [B,Q]
    float* out = (float*)d_out;                   // [B,Q,Q] f32

    hungarian_cost_kernel<<<Bn * NIT, BLK, 0, stream>>>(
        logits, pboxes, gboxes, areas, labels, out);
}